// Round 2
// baseline (292.538 us; speedup 1.0000x reference)
//
#include <hip/hip_runtime.h>
#include <hip/hip_fp16.h>

// ---------------------------------------------------------------------------
// IN=128, H=8, R=16, D=16 -> H*R = H*D = 128
// K = h @ q, Q = h @ p, V = h @ Wv   (K uses weight "q", Q uses weight "p")
// score = exp(clip((K[src]*Q[dst]).sum(r)/4, -5, 5))
// out = seg_sum(score*V[src], dst) / max(seg_sum(score,dst), eps-fixup)
//
// R12: gemm & scatter are tiny-grid latency chains -> one mixed dispatch.
// R13: head-per-XCD aggregation (head = blockIdx&7): per-head KV slice is
//      3.2MB -> fits one XCD's 4MiB L2. FETCH 350MB -> 55MB (verified).
// R14: aggregate was VALU-issue-bound (88% busy): 4-lane/edge split + 16-edge
//      granularity + per-16 chunk machinery cost ~140 lane-ops/edge-head.
//      Rework: 1 lane = 1 edge-head (whole 64B gather, 8 lane-local fdot2,
//      NO shuffles in loop, direct csr loads), wave = 16 nodes x 4 slots,
//      nodes degree-sorted per bucket so divergent loops finish together.
// ---------------------------------------------------------------------------

#define HNODE 64        // nodes per GEMM block
#define EPB   4096      // edges per scatter block (short chains, more blocks)
#define BKT_SHIFT 7     // 128 nodes per bucket
#define BKT_CAP 5120    // bucket mean 4092 + 16 sigma
#define CHUNK 40        // per-(bucket,block) slots; Poisson(10.5)+9sigma

typedef _Float16 f16x8 __attribute__((ext_vector_type(8)));
typedef float    f32x4 __attribute__((ext_vector_type(4)));
typedef _Float16 hv2   __attribute__((ext_vector_type(2)));

__device__ __forceinline__ float fdot2(unsigned a, unsigned b, float c) {
#if __has_builtin(__builtin_amdgcn_fdot2)
    return __builtin_amdgcn_fdot2(__builtin_bit_cast(hv2, a),
                                  __builtin_bit_cast(hv2, b), c, false);
#else
    __half2 ah = *(__half2*)&a, bh = *(__half2*)&b;
    float2 af = __half22float2(ah), bf = __half22float2(bh);
    return c + af.x * bf.x + af.y * bf.y;
#endif
}

__device__ __forceinline__ float2 h2f(unsigned u) {
    __half2 hh = *(__half2*)&u;
    return __half22float2(hh);
}

__device__ __forceinline__ unsigned pack2(float a, float b) {
    __half2 hh = __floats2half2_rn(a, b);
    return *(unsigned*)&hh;
}

// ---------------- D0: weight transpose+convert W[k][n] fp32 -> Wt[m][n][k] --
__global__ __launch_bounds__(256) void wt_convert_kernel(
    const float* __restrict__ Wq, const float* __restrict__ Wp,
    const float* __restrict__ Wv, __half* __restrict__ Wt)
{
    int o = blockIdx.x * 256 + threadIdx.x;      // 3*128*128 total
    int m = o >> 14, rem = o & 16383;
    int nn = rem >> 7, kk = rem & 127;
    const float* W = (m == 0) ? Wq : (m == 1) ? Wp : Wv;
    Wt[o] = __float2half(W[kk * 128 + nn]);
}

// ---------------- D1: mixed dispatch -- gemm blocks + scatter blocks --------
__global__ __launch_bounds__(256) void gemm_scatter_kernel(
    const float* __restrict__ h, const __half* __restrict__ Wt,
    unsigned* __restrict__ KV, __half* __restrict__ Q, int n,
    const int* __restrict__ src, const int* __restrict__ dst,
    unsigned* __restrict__ ebuf, int* __restrict__ cnts,
    int E, int nbkt, int nblk_e, int gemm_blocks)
{
    __shared__ __align__(16) char smem[39936];
    const int t = threadIdx.x;

    if ((int)blockIdx.x < gemm_blocks) {
        // ------------------ GEMM branch (MFMA 16x16x32 f16) ------------------
        _Float16* ws = (_Float16*)smem;            // 128 x 136 halves
        const int wid = t >> 6, lane = t & 63;
        const int node0 = blockIdx.x * HNODE;
        const int mrow = lane & 15, quad = lane >> 4;

        const int row = node0 + wid * 16 + mrow;
        const bool rowvalid = (row < n);
        const int rowc = rowvalid ? row : (n - 1);

        f16x8 hfr[4];
        #pragma unroll
        for (int s = 0; s < 4; s++) {
            const float4* hp = (const float4*)(h + (size_t)rowc * 128 + quad * 8 + 32 * s);
            float4 f0 = hp[0], f1 = hp[1];
            f16x8 a;
            a[0] = (_Float16)f0.x; a[1] = (_Float16)f0.y;
            a[2] = (_Float16)f0.z; a[3] = (_Float16)f0.w;
            a[4] = (_Float16)f1.x; a[5] = (_Float16)f1.y;
            a[6] = (_Float16)f1.z; a[7] = (_Float16)f1.w;
            hfr[s] = a;
        }

        f32x4 acc[3][8];
        #pragma unroll
        for (int m = 0; m < 3; m++)
            #pragma unroll
            for (int ct = 0; ct < 8; ct++) acc[m][ct] = (f32x4){0.f, 0.f, 0.f, 0.f};

        #pragma unroll
        for (int m = 0; m < 3; m++) {
            __syncthreads();
            {
                const uint4* wg = (const uint4*)(Wt + (size_t)m * 16384);
                #pragma unroll
                for (int i = 0; i < 8; i++) {
                    int idx = t * 8 + i;            // 0..2047
                    int r = idx >> 4, seg = idx & 15;
                    *(uint4*)(ws + r * 136 + seg * 8) = wg[idx];
                }
            }
            __syncthreads();
            #pragma unroll
            for (int s = 0; s < 4; s++) {
                #pragma unroll
                for (int ct = 0; ct < 8; ct++) {
                    f16x8 a = *(const f16x8*)(ws + (ct * 16 + mrow) * 136 + quad * 8 + 32 * s);
                    acc[m][ct] = __builtin_amdgcn_mfma_f32_16x16x32_f16(a, hfr[s], acc[m][ct], 0, 0, 0);
                }
            }
        }

        if (rowvalid) {
            // head-major epilogue: for MFMA tile ct, head = ct, quarter = quad
            #pragma unroll
            for (int ct = 0; ct < 8; ct++) {
                uint4 ov;
                ov.x = pack2(acc[0][ct][0], acc[0][ct][1]);   // K pair
                ov.y = pack2(acc[0][ct][2], acc[0][ct][3]);
                ov.z = pack2(acc[2][ct][0], acc[2][ct][1]);   // V pair
                ov.w = pack2(acc[2][ct][2], acc[2][ct][3]);
                *(uint4*)(KV + (((size_t)ct * n + row) << 4) + 4 * quad) = ov;
                uint2 qv;
                qv.x = pack2(acc[1][ct][0], acc[1][ct][1]);
                qv.y = pack2(acc[1][ct][2], acc[1][ct][3]);
                *(uint2*)(Q + (((size_t)ct * n + row) << 4) + 4 * quad) = qv;
            }
        }
    } else {
        // ------------------ scatter branch (bucket sort in LDS) --------------
        unsigned long long* sorted = (unsigned long long*)smem;   // 4096 (32KB)
        int* cnt  = (int*)(smem + 32768);                         // 512
        int* lofs = (int*)(smem + 34816);                         // 512
        int* ts   = (int*)(smem + 36864);                         // 256
        int* tot_sh = (int*)(smem + 37888);

        int blk = blockIdx.x - gemm_blocks;
        for (int i = t; i < 512; i += 256) cnt[i] = 0;
        __syncthreads();

        int4 sv[4], dv[4], rk[4];
        int base = blk * EPB + t * 4;
        #pragma unroll
        for (int r = 0; r < 4; r++) {
            int i = base + r * 1024;
            if (i + 3 < E) {
                sv[r] = *(const int4*)(src + i);
                dv[r] = *(const int4*)(dst + i);
            } else {
                int tsrc[4], tdst[4];
                for (int k = 0; k < 4; k++) {
                    int j = i + k;
                    tsrc[k] = (j < E) ? src[j] : 0;
                    tdst[k] = (j < E) ? dst[j] : -1;
                }
                sv[r] = make_int4(tsrc[0], tsrc[1], tsrc[2], tsrc[3]);
                dv[r] = make_int4(tdst[0], tdst[1], tdst[2], tdst[3]);
            }
            rk[r].x = (dv[r].x >= 0) ? atomicAdd(&cnt[dv[r].x >> BKT_SHIFT], 1) : 0;
            rk[r].y = (dv[r].y >= 0) ? atomicAdd(&cnt[dv[r].y >> BKT_SHIFT], 1) : 0;
            rk[r].z = (dv[r].z >= 0) ? atomicAdd(&cnt[dv[r].z >> BKT_SHIFT], 1) : 0;
            rk[r].w = (dv[r].w >= 0) ? atomicAdd(&cnt[dv[r].w >> BKT_SHIFT], 1) : 0;
        }
        __syncthreads();

        for (int i = t; i < nbkt; i += 256)
            cnts[blk * 512 + i] = cnt[i];

        // exclusive scan over 512 bucket counts (thread t owns 2t, 2t+1)
        int c0 = cnt[2 * t], c1 = cnt[2 * t + 1];
        int ps = c0 + c1;
        ts[t] = ps; __syncthreads();
        for (int off = 1; off < 256; off <<= 1) {
            int x = ts[t];
            int y = (t >= off) ? ts[t - off] : 0;
            __syncthreads();
            ts[t] = x + y;
            __syncthreads();
        }
        int pbase = ts[t] - ps;
        lofs[2 * t] = pbase;
        lofs[2 * t + 1] = pbase + c0;
        if (t == 255) *tot_sh = ts[255];
        __syncthreads();

        #pragma unroll
        for (int r = 0; r < 4; r++) {
            int s, d;
            d = dv[r].x; if (d >= 0) { s = sv[r].x; sorted[lofs[d >> BKT_SHIFT] + rk[r].x] = ((unsigned long long)d << 18) | (unsigned)s; }
            d = dv[r].y; if (d >= 0) { s = sv[r].y; sorted[lofs[d >> BKT_SHIFT] + rk[r].y] = ((unsigned long long)d << 18) | (unsigned)s; }
            d = dv[r].z; if (d >= 0) { s = sv[r].z; sorted[lofs[d >> BKT_SHIFT] + rk[r].z] = ((unsigned long long)d << 18) | (unsigned)s; }
            d = dv[r].w; if (d >= 0) { s = sv[r].w; sorted[lofs[d >> BKT_SHIFT] + rk[r].w] = ((unsigned long long)d << 18) | (unsigned)s; }
        }
        __syncthreads();

        int tot = *tot_sh;
        #pragma unroll
        for (int j = 0; j < 16; j++) {
            int i = j * 256 + t;
            if (i < tot) {
                unsigned long long e = sorted[i];
                int d = (int)(e >> 18);
                int b = d >> BKT_SHIFT;
                int k = i - lofs[b];
                if (k < CHUNK)
                    ebuf[((size_t)b * nblk_e + blk) * CHUNK + k] =
                        ((unsigned)(d & 127) << 18) | (unsigned)(e & 0x3FFFFu);
            }
        }
    }
}

// ---------------- D2: per-bucket fine sort -> csr + offs + degree order -----
__global__ __launch_bounds__(512) void fine_scatter_kernel(
    const unsigned* __restrict__ ebuf, const int* __restrict__ cnts,
    int2* __restrict__ offs, int* __restrict__ csr, int* __restrict__ nodeord,
    int N, int nblk_e, int nbkt)
{
    __shared__ int cval[512];
    __shared__ int cofs[512];
    __shared__ int ts[512];
    __shared__ int ldeg[128];
    __shared__ int lstart[129];
    __shared__ int tot_sh;
    __shared__ unsigned sedge[BKT_CAP];
    __shared__ unsigned short srank[BKT_CAP];
    __shared__ int lcsr[BKT_CAP];

    int b = blockIdx.x, t = threadIdx.x;
    int node_base = b << BKT_SHIFT;
    int seg0 = b * BKT_CAP;

    int c = (t < nblk_e) ? cnts[t * 512 + b] : 0;
    if (c > CHUNK) c = CHUNK;
    cval[t] = c;
    ts[t] = c;
    if (t < 128) ldeg[t] = 0;
    __syncthreads();
    for (int off = 1; off < 512; off <<= 1) {
        int x = ts[t];
        int y = (t >= off) ? ts[t - off] : 0;
        __syncthreads();
        ts[t] = x + y;
        __syncthreads();
    }
    cofs[t] = ts[t] - cval[t];
    if (t == 511) tot_sh = (ts[511] <= BKT_CAP) ? ts[511] : BKT_CAP;
    __syncthreads();

    for (int idx = t; idx < nblk_e * CHUNK; idx += 512) {
        int cc = idx / CHUNK, k = idx - cc * CHUNK;
        if (k < cval[cc]) {
            int pos = cofs[cc] + k;
            if (pos < BKT_CAP)
                sedge[pos] = ebuf[((size_t)b * nblk_e + cc) * CHUNK + k];
        }
    }
    __syncthreads();

    int tot = tot_sh;
    for (int i = t; i < tot; i += 512)
        srank[i] = (unsigned short)atomicAdd(&ldeg[sedge[i] >> 18], 1);
    __syncthreads();

    int mydeg = (t < 128) ? ldeg[t] : 0;
    if (t < 128) ts[t] = mydeg;
    __syncthreads();
    for (int off = 1; off < 128; off <<= 1) {
        int x = (t < 128) ? ts[t] : 0;
        int y = (t >= off && t < 128) ? ts[t - off] : 0;
        __syncthreads();
        if (t < 128) ts[t] = x + y;
        __syncthreads();
    }
    if (t < 128) {
        int lbeg = ts[t] - mydeg;
        lstart[t] = lbeg;
        int node = node_base + t;
        if (node < N) offs[node] = make_int2(seg0 + lbeg, seg0 + lbeg + mydeg);
    }
    if (t == 127) lstart[128] = ts[127];
    __syncthreads();

    // R14: stable descending-degree rank of the 128 local nodes -> nodeord.
    // Aggregate waves take 16 consecutive sorted nodes, so divergent edge
    // loops finish together (minimize max-vs-mean degree waste).
    if (t < 128) {
        int dt = ldeg[t];
        int r = 0;
        for (int j = 0; j < 128; j++) {
            int dj = ldeg[j];
            r += (int)((dj > dt) || (dj == dt && j < t));
        }
        nodeord[(b << 7) + r] = t;
    }

    for (int i = t; i < tot; i += 512) {
        unsigned v = sedge[i];
        lcsr[lstart[v >> 18] + srank[i]] = (int)(v & 0x3FFFFu);
    }
    __syncthreads();

    for (int i = t; i < tot; i += 512)
        csr[seg0 + i] = lcsr[i];
}

// ---------------- D3: aggregation, head-per-XCD, lane-per-edge --------------
// grid = nbkt * 2 * 8; head = blockIdx&7 (XCD pin), block = 64 sorted nodes
// of one bucket for one head. wave = 16 nodes x 4 edge slots; each lane owns
// a full edge-head: gathers all 64B of KV[h][src], 8 lane-local fdot2, exp,
// 16 f32 FMAs. No shuffles in the loop; csr indices loaded directly.
__global__ __launch_bounds__(256) void aggregate_kernel(
    const uint4* __restrict__ KVh,   // [H][N][4] uint4 (64B per node-head)
    const uint4* __restrict__ Qh,    // [H][N][2] uint4 (32B per node-head)
    const int2* __restrict__ offs, const int* __restrict__ csr,
    const int* __restrict__ nodeord,
    float4* __restrict__ out, int n)
{
    const int t = threadIdx.x;
    const int head = blockIdx.x & 7;
    const int rest = blockIdx.x >> 3;
    const int bkt = rest >> 1, sub = rest & 1;
    const int lane = t & 63;
    const int slot = lane & 3;
    const int spos = (bkt << 7) + (sub << 6) + ((t >> 6) << 4) + (lane >> 2);

    const int local = nodeord[spos];
    const int node = (bkt << 7) + local;
    const bool nvalid = (node < n);

    int beg = 0, cnt = 0;
    if (nvalid) {
        int2 be = offs[node];
        beg = be.x; cnt = be.y - be.x;
    }

    const size_t hn = (size_t)head * n;
    const uint4* qp = Qh + (hn + (size_t)(nvalid ? node : 0)) * 2;
    const uint4 q0 = qp[0], q1 = qp[1];

    float accz = 0.f;
    float av[16];
    #pragma unroll
    for (int k = 0; k < 16; k++) av[k] = 0.f;

    // software pipeline depth 1: idx + 64B KV for the current 4-edge group
    int idxA = 0;
    if (slot < cnt) idxA = csr[beg + slot];
    const uint4* kp = KVh + (hn + (size_t)idxA) * 4;
    uint4 a0 = kp[0], a1 = kp[1], a2 = kp[2], a3 = kp[3];

    for (int e = 0; e < cnt; e += 4) {
        // branchless prefetch of next group (clamped index; cnt>0 inside loop)
        int npos = e + 4 + slot;
        int ip = (npos < cnt) ? npos : 0;
        int idxB = csr[beg + ip];
        const uint4* np = KVh + (hn + (size_t)idxB) * 4;
        uint4 b0 = np[0], b1 = np[1], b2 = np[2], b3 = np[3];

        // score: full 16-dim K.Q, lane-local
        float p = fdot2(a0.y, q0.y, fdot2(a0.x, q0.x, 0.f));
        p = fdot2(a1.y, q0.w, fdot2(a1.x, q0.z, p));
        p = fdot2(a2.y, q1.y, fdot2(a2.x, q1.x, p));
        p = fdot2(a3.y, q1.w, fdot2(a3.x, q1.z, p));
        float x = fminf(fmaxf(p * 0.25f, -5.f), 5.f);
        float sc = (e + slot < cnt) ? __expf(x) : 0.f;
        accz += sc;

        float2 v;
        v = h2f(a0.z); av[0]  += sc * v.x; av[1]  += sc * v.y;
        v = h2f(a0.w); av[2]  += sc * v.x; av[3]  += sc * v.y;
        v = h2f(a1.z); av[4]  += sc * v.x; av[5]  += sc * v.y;
        v = h2f(a1.w); av[6]  += sc * v.x; av[7]  += sc * v.y;
        v = h2f(a2.z); av[8]  += sc * v.x; av[9]  += sc * v.y;
        v = h2f(a2.w); av[10] += sc * v.x; av[11] += sc * v.y;
        v = h2f(a3.z); av[12] += sc * v.x; av[13] += sc * v.y;
        v = h2f(a3.w); av[14] += sc * v.x; av[15] += sc * v.y;

        a0 = b0; a1 = b1; a2 = b2; a3 = b3;
    }

    // reduce across the 4 slot lanes (lane bits 0-1 only)
    #pragma unroll
    for (int m = 1; m <= 2; m <<= 1) {
        accz += __shfl_xor(accz, m);
        #pragma unroll
        for (int k = 0; k < 16; k++) av[k] += __shfl_xor(av[k], m);
    }

    if (nvalid && slot == 0) {
        if (accz == 0.f) accz = 0.001f;
        float inv = 1.0f / accz;
        float4* op = out + (size_t)node * 32 + head * 4;
        op[0] = make_float4(av[0] * inv, av[1] * inv, av[2] * inv, av[3] * inv);
        op[1] = make_float4(av[4] * inv, av[5] * inv, av[6] * inv, av[7] * inv);
        op[2] = make_float4(av[8] * inv, av[9] * inv, av[10] * inv, av[11] * inv);
        op[3] = make_float4(av[12] * inv, av[13] * inv, av[14] * inv, av[15] * inv);
    }
}

// ---------------------------------------------------------------------------

extern "C" void kernel_launch(void* const* d_in, const int* in_sizes, int n_in,
                              void* d_out, int out_size, void* d_ws, size_t ws_size,
                              hipStream_t stream)
{
    const float* h   = (const float*)d_in[0];
    const int*   src = (const int*)d_in[1];
    const int*   dst = (const int*)d_in[2];
    const float* p   = (const float*)d_in[3];
    const float* q   = (const float*)d_in[4];
    const float* wv  = (const float*)d_in[5];
    float* out = (float*)d_out;

    const int N = in_sizes[0] / 128;
    const int E = in_sizes[1];
    const int nbkt = (N + 127) >> BKT_SHIFT;     // 391 for N=50000 (<=512)
    const int nblk_e = (E + EPB - 1) / EPB;      // 391 for E=1.6M (<=512)
    const int gemm_blocks = (N + HNODE - 1) / HNODE;   // 782

    unsigned* KV = (unsigned*)d_ws;                            // H*N*16 u32 (25.6MB)
    __half* Qh   = (__half*)(KV + (size_t)N * 128);            // H*N*16 half (12.8MB)
    unsigned* ebuf = (unsigned*)(Qh + (size_t)N * 128);        // nbkt*nblk_e*CHUNK u32 (~24.5MB)
    int* cnts    = (int*)(ebuf + (size_t)nbkt * nblk_e * CHUNK); // nblk_e*512
    int* csr     = cnts + (size_t)nblk_e * 512;                // nbkt*BKT_CAP (8MB)
    int2* offs   = (int2*)(csr + (size_t)nbkt * BKT_CAP);      // N
    int* nodeord = (int*)(offs + N);                           // nbkt*128
    __half* Wt   = (__half*)(nodeord + (size_t)nbkt * 128);    // 3*128*128 halves

    wt_convert_kernel<<<192, 256, 0, stream>>>(q, p, wv, Wt);

    gemm_scatter_kernel<<<gemm_blocks + nblk_e, 256, 0, stream>>>(
        h, Wt, KV, Qh, N, src, dst, ebuf, cnts, E, nbkt, nblk_e, gemm_blocks);

    fine_scatter_kernel<<<nbkt, 512, 0, stream>>>(ebuf, cnts, offs, csr, nodeord, N, nblk_e, nbkt);

    aggregate_kernel<<<nbkt * 16, 256, 0, stream>>>(
        (const uint4*)KV, (const uint4*)Qh, offs, csr, nodeord, (float4*)out, N);
}

// Round 3
// 227.935 us; speedup vs baseline: 1.2834x; 1.2834x over previous
//
#include <hip/hip_runtime.h>
#include <hip/hip_fp16.h>

// ---------------------------------------------------------------------------
// IN=128, H=8, R=16, D=16 -> H*R = H*D = 128
// K = h @ q, Q = h @ p, V = h @ Wv   (K uses weight "q", Q uses weight "p")
// score = exp(clip((K[src]*Q[dst]).sum(r)/4, -5, 5))
// out = seg_sum(score*V[src], dst) / max(seg_sum(score,dst), eps-fixup)
//
// R12: gemm & scatter are tiny-grid latency chains -> one mixed dispatch.
// R13: head-per-XCD aggregation (head = blockIdx&7): per-head KV slice is
//      3.2MB -> fits one XCD's 4MiB L2. FETCH 350MB -> 55MB (verified).
// R14: lane-per-edge gather killed VALU (88%->16%) but quadrupled TA
//      line-touches (4x dwordx4 per row) -> latency-bound at 150us.
// R15: quad-per-edge. KV row is quarter-interleaved {K8B,V8B}x4, so lane p
//      takes quarter p: ONE gather instr per 16 edge-heads (1 line-touch
//      each), every lane does useful K-dot AND V-FMA work. Cross-lane via
//      DPP quad_perm (VALU, no LDS): 2 xor-adds + 1 csr-idx broadcast.
//      csr stored u16 (N<65536). nodeord chunks interleaved across the two
//      sub-blocks so degree-sorted blocks finish together.
// ---------------------------------------------------------------------------

#define HNODE 64        // nodes per GEMM block
#define EPB   4096      // edges per scatter block (short chains, more blocks)
#define BKT_SHIFT 7     // 128 nodes per bucket
#define BKT_CAP 5120    // bucket mean 4092 + 16 sigma
#define CHUNK 40        // per-(bucket,block) slots; Poisson(10.5)+9sigma

typedef _Float16 f16x8 __attribute__((ext_vector_type(8)));
typedef float    f32x4 __attribute__((ext_vector_type(4)));
typedef _Float16 hv2   __attribute__((ext_vector_type(2)));

__device__ __forceinline__ float fdot2(unsigned a, unsigned b, float c) {
#if __has_builtin(__builtin_amdgcn_fdot2)
    return __builtin_amdgcn_fdot2(__builtin_bit_cast(hv2, a),
                                  __builtin_bit_cast(hv2, b), c, false);
#else
    __half2 ah = *(__half2*)&a, bh = *(__half2*)&b;
    float2 af = __half22float2(ah), bf = __half22float2(bh);
    return c + af.x * bf.x + af.y * bf.y;
#endif
}

__device__ __forceinline__ float2 h2f(unsigned u) {
    __half2 hh = *(__half2*)&u;
    return __half22float2(hh);
}

__device__ __forceinline__ unsigned pack2(float a, float b) {
    __half2 hh = __floats2half2_rn(a, b);
    return *(unsigned*)&hh;
}

// ---- quad-scope cross-lane via DPP (VALU pipe, no LDS traffic) -------------
#if __has_builtin(__builtin_amdgcn_mov_dpp)
#define QBCAST(v, J) __builtin_amdgcn_mov_dpp((v), (J) * 0x55, 0xF, 0xF, true)
__device__ __forceinline__ float qadd_xor1(float x) {
    int y = __builtin_amdgcn_mov_dpp(__float_as_int(x), 0xB1, 0xF, 0xF, true);
    return x + __int_as_float(y);
}
__device__ __forceinline__ float qadd_xor2(float x) {
    int y = __builtin_amdgcn_mov_dpp(__float_as_int(x), 0x4E, 0xF, 0xF, true);
    return x + __int_as_float(y);
}
#else
#define QBCAST(v, J) __shfl((v), ((threadIdx.x & 63) & ~3) + (J), 64)
__device__ __forceinline__ float qadd_xor1(float x) { return x + __shfl_xor(x, 1); }
__device__ __forceinline__ float qadd_xor2(float x) { return x + __shfl_xor(x, 2); }
#endif

// ---------------- D0: weight transpose+convert W[k][n] fp32 -> Wt[m][n][k] --
__global__ __launch_bounds__(256) void wt_convert_kernel(
    const float* __restrict__ Wq, const float* __restrict__ Wp,
    const float* __restrict__ Wv, __half* __restrict__ Wt)
{
    int o = blockIdx.x * 256 + threadIdx.x;      // 3*128*128 total
    int m = o >> 14, rem = o & 16383;
    int nn = rem >> 7, kk = rem & 127;
    const float* W = (m == 0) ? Wq : (m == 1) ? Wp : Wv;
    Wt[o] = __float2half(W[kk * 128 + nn]);
}

// ---------------- D1: mixed dispatch -- gemm blocks + scatter blocks --------
__global__ __launch_bounds__(256) void gemm_scatter_kernel(
    const float* __restrict__ h, const __half* __restrict__ Wt,
    unsigned* __restrict__ KV, __half* __restrict__ Q, int n,
    const int* __restrict__ src, const int* __restrict__ dst,
    unsigned* __restrict__ ebuf, int* __restrict__ cnts,
    int E, int nbkt, int nblk_e, int gemm_blocks)
{
    __shared__ __align__(16) char smem[39936];
    const int t = threadIdx.x;

    if ((int)blockIdx.x < gemm_blocks) {
        // ------------------ GEMM branch (MFMA 16x16x32 f16) ------------------
        _Float16* ws = (_Float16*)smem;            // 128 x 136 halves
        const int wid = t >> 6, lane = t & 63;
        const int node0 = blockIdx.x * HNODE;
        const int mrow = lane & 15, quad = lane >> 4;

        const int row = node0 + wid * 16 + mrow;
        const bool rowvalid = (row < n);
        const int rowc = rowvalid ? row : (n - 1);

        f16x8 hfr[4];
        #pragma unroll
        for (int s = 0; s < 4; s++) {
            const float4* hp = (const float4*)(h + (size_t)rowc * 128 + quad * 8 + 32 * s);
            float4 f0 = hp[0], f1 = hp[1];
            f16x8 a;
            a[0] = (_Float16)f0.x; a[1] = (_Float16)f0.y;
            a[2] = (_Float16)f0.z; a[3] = (_Float16)f0.w;
            a[4] = (_Float16)f1.x; a[5] = (_Float16)f1.y;
            a[6] = (_Float16)f1.z; a[7] = (_Float16)f1.w;
            hfr[s] = a;
        }

        f32x4 acc[3][8];
        #pragma unroll
        for (int m = 0; m < 3; m++)
            #pragma unroll
            for (int ct = 0; ct < 8; ct++) acc[m][ct] = (f32x4){0.f, 0.f, 0.f, 0.f};

        #pragma unroll
        for (int m = 0; m < 3; m++) {
            __syncthreads();
            {
                const uint4* wg = (const uint4*)(Wt + (size_t)m * 16384);
                #pragma unroll
                for (int i = 0; i < 8; i++) {
                    int idx = t * 8 + i;            // 0..2047
                    int r = idx >> 4, seg = idx & 15;
                    *(uint4*)(ws + r * 136 + seg * 8) = wg[idx];
                }
            }
            __syncthreads();
            #pragma unroll
            for (int s = 0; s < 4; s++) {
                #pragma unroll
                for (int ct = 0; ct < 8; ct++) {
                    f16x8 a = *(const f16x8*)(ws + (ct * 16 + mrow) * 136 + quad * 8 + 32 * s);
                    acc[m][ct] = __builtin_amdgcn_mfma_f32_16x16x32_f16(a, hfr[s], acc[m][ct], 0, 0, 0);
                }
            }
        }

        if (rowvalid) {
            // head-major epilogue: for MFMA tile ct, head = ct, quarter = quad
            #pragma unroll
            for (int ct = 0; ct < 8; ct++) {
                uint4 ov;
                ov.x = pack2(acc[0][ct][0], acc[0][ct][1]);   // K pair
                ov.y = pack2(acc[0][ct][2], acc[0][ct][3]);
                ov.z = pack2(acc[2][ct][0], acc[2][ct][1]);   // V pair
                ov.w = pack2(acc[2][ct][2], acc[2][ct][3]);
                *(uint4*)(KV + (((size_t)ct * n + row) << 4) + 4 * quad) = ov;
                uint2 qv;
                qv.x = pack2(acc[1][ct][0], acc[1][ct][1]);
                qv.y = pack2(acc[1][ct][2], acc[1][ct][3]);
                *(uint2*)(Q + (((size_t)ct * n + row) << 4) + 4 * quad) = qv;
            }
        }
    } else {
        // ------------------ scatter branch (bucket sort in LDS) --------------
        unsigned long long* sorted = (unsigned long long*)smem;   // 4096 (32KB)
        int* cnt  = (int*)(smem + 32768);                         // 512
        int* lofs = (int*)(smem + 34816);                         // 512
        int* ts   = (int*)(smem + 36864);                         // 256
        int* tot_sh = (int*)(smem + 37888);

        int blk = blockIdx.x - gemm_blocks;
        for (int i = t; i < 512; i += 256) cnt[i] = 0;
        __syncthreads();

        int4 sv[4], dv[4], rk[4];
        int base = blk * EPB + t * 4;
        #pragma unroll
        for (int r = 0; r < 4; r++) {
            int i = base + r * 1024;
            if (i + 3 < E) {
                sv[r] = *(const int4*)(src + i);
                dv[r] = *(const int4*)(dst + i);
            } else {
                int tsrc[4], tdst[4];
                for (int k = 0; k < 4; k++) {
                    int j = i + k;
                    tsrc[k] = (j < E) ? src[j] : 0;
                    tdst[k] = (j < E) ? dst[j] : -1;
                }
                sv[r] = make_int4(tsrc[0], tsrc[1], tsrc[2], tsrc[3]);
                dv[r] = make_int4(tdst[0], tdst[1], tdst[2], tdst[3]);
            }
            rk[r].x = (dv[r].x >= 0) ? atomicAdd(&cnt[dv[r].x >> BKT_SHIFT], 1) : 0;
            rk[r].y = (dv[r].y >= 0) ? atomicAdd(&cnt[dv[r].y >> BKT_SHIFT], 1) : 0;
            rk[r].z = (dv[r].z >= 0) ? atomicAdd(&cnt[dv[r].z >> BKT_SHIFT], 1) : 0;
            rk[r].w = (dv[r].w >= 0) ? atomicAdd(&cnt[dv[r].w >> BKT_SHIFT], 1) : 0;
        }
        __syncthreads();

        for (int i = t; i < nbkt; i += 256)
            cnts[blk * 512 + i] = cnt[i];

        // exclusive scan over 512 bucket counts (thread t owns 2t, 2t+1)
        int c0 = cnt[2 * t], c1 = cnt[2 * t + 1];
        int ps = c0 + c1;
        ts[t] = ps; __syncthreads();
        for (int off = 1; off < 256; off <<= 1) {
            int x = ts[t];
            int y = (t >= off) ? ts[t - off] : 0;
            __syncthreads();
            ts[t] = x + y;
            __syncthreads();
        }
        int pbase = ts[t] - ps;
        lofs[2 * t] = pbase;
        lofs[2 * t + 1] = pbase + c0;
        if (t == 255) *tot_sh = ts[255];
        __syncthreads();

        #pragma unroll
        for (int r = 0; r < 4; r++) {
            int s, d;
            d = dv[r].x; if (d >= 0) { s = sv[r].x; sorted[lofs[d >> BKT_SHIFT] + rk[r].x] = ((unsigned long long)d << 18) | (unsigned)s; }
            d = dv[r].y; if (d >= 0) { s = sv[r].y; sorted[lofs[d >> BKT_SHIFT] + rk[r].y] = ((unsigned long long)d << 18) | (unsigned)s; }
            d = dv[r].z; if (d >= 0) { s = sv[r].z; sorted[lofs[d >> BKT_SHIFT] + rk[r].z] = ((unsigned long long)d << 18) | (unsigned)s; }
            d = dv[r].w; if (d >= 0) { s = sv[r].w; sorted[lofs[d >> BKT_SHIFT] + rk[r].w] = ((unsigned long long)d << 18) | (unsigned)s; }
        }
        __syncthreads();

        int tot = *tot_sh;
        #pragma unroll
        for (int j = 0; j < 16; j++) {
            int i = j * 256 + t;
            if (i < tot) {
                unsigned long long e = sorted[i];
                int d = (int)(e >> 18);
                int b = d >> BKT_SHIFT;
                int k = i - lofs[b];
                if (k < CHUNK)
                    ebuf[((size_t)b * nblk_e + blk) * CHUNK + k] =
                        ((unsigned)(d & 127) << 18) | (unsigned)(e & 0x3FFFFu);
            }
        }
    }
}

// ---------------- D2: per-bucket fine sort -> csr(u16) + offs + order -------
__global__ __launch_bounds__(512) void fine_scatter_kernel(
    const unsigned* __restrict__ ebuf, const int* __restrict__ cnts,
    int2* __restrict__ offs, unsigned short* __restrict__ csr,
    int* __restrict__ nodeord, int N, int nblk_e, int nbkt)
{
    __shared__ int cval[512];
    __shared__ int cofs[512];
    __shared__ int ts[512];
    __shared__ int ldeg[128];
    __shared__ int lstart[129];
    __shared__ int tot_sh;
    __shared__ unsigned sedge[BKT_CAP];
    __shared__ unsigned short srank[BKT_CAP];
    __shared__ int lcsr[BKT_CAP];

    int b = blockIdx.x, t = threadIdx.x;
    int node_base = b << BKT_SHIFT;
    int seg0 = b * BKT_CAP;

    int c = (t < nblk_e) ? cnts[t * 512 + b] : 0;
    if (c > CHUNK) c = CHUNK;
    cval[t] = c;
    ts[t] = c;
    if (t < 128) ldeg[t] = 0;
    __syncthreads();
    for (int off = 1; off < 512; off <<= 1) {
        int x = ts[t];
        int y = (t >= off) ? ts[t - off] : 0;
        __syncthreads();
        ts[t] = x + y;
        __syncthreads();
    }
    cofs[t] = ts[t] - cval[t];
    if (t == 511) tot_sh = (ts[511] <= BKT_CAP) ? ts[511] : BKT_CAP;
    __syncthreads();

    for (int idx = t; idx < nblk_e * CHUNK; idx += 512) {
        int cc = idx / CHUNK, k = idx - cc * CHUNK;
        if (k < cval[cc]) {
            int pos = cofs[cc] + k;
            if (pos < BKT_CAP)
                sedge[pos] = ebuf[((size_t)b * nblk_e + cc) * CHUNK + k];
        }
    }
    __syncthreads();

    int tot = tot_sh;
    for (int i = t; i < tot; i += 512)
        srank[i] = (unsigned short)atomicAdd(&ldeg[sedge[i] >> 18], 1);
    __syncthreads();

    int mydeg = (t < 128) ? ldeg[t] : 0;
    if (t < 128) ts[t] = mydeg;
    __syncthreads();
    for (int off = 1; off < 128; off <<= 1) {
        int x = (t < 128) ? ts[t] : 0;
        int y = (t >= off && t < 128) ? ts[t - off] : 0;
        __syncthreads();
        if (t < 128) ts[t] = x + y;
        __syncthreads();
    }
    if (t < 128) {
        int lbeg = ts[t] - mydeg;
        lstart[t] = lbeg;
        int node = node_base + t;
        if (node < N) offs[node] = make_int2(seg0 + lbeg, seg0 + lbeg + mydeg);
    }
    if (t == 127) lstart[128] = ts[127];
    __syncthreads();

    // stable descending-degree rank of the 128 local nodes -> nodeord
    if (t < 128) {
        int dt = ldeg[t];
        int r = 0;
        for (int j = 0; j < 128; j++) {
            int dj = ldeg[j];
            r += (int)((dj > dt) || (dj == dt && j < t));
        }
        nodeord[(b << 7) + r] = t;
    }

    for (int i = t; i < tot; i += 512) {
        unsigned v = sedge[i];
        lcsr[lstart[v >> 18] + srank[i]] = (int)(v & 0x3FFFFu);
    }
    __syncthreads();

    for (int i = t; i < tot; i += 512)
        csr[seg0 + i] = (unsigned short)lcsr[i];
}

// ---------------- D3: aggregation, head-per-XCD, quad-per-edge --------------
// grid = nbkt*2*8; head = blockIdx&7 (XCD pin). Block = 64 degree-similar
// nodes of one bucket (rank chunks interleaved across the two sub-blocks).
// Wave = 16 quads; quad = one node, lane p = feature quarter p.
// Per step each quad processes 1 edge: ONE 64B row gather (4 lanes x 16B,
// single line-touch), 2 fdot2 + DPP quad-reduce, exp, 4 V-FMAs per lane.
// csr (u16) loaded 4-ahead per quad, distributed via DPP broadcast.
#define AGG_STEP(J, RELOAD)                                                    \
    {                                                                          \
        int inext;                                                             \
        if (RELOAD) {                                                          \
            int np = e + 4 + p; np = (np < cl) ? np : cl;                      \
            idxq = (int)csr[beg + np];                                         \
            inext = QBCAST(idxq, 0);                                           \
        } else {                                                               \
            inext = QBCAST(idxq, (J) + 1);                                     \
        }                                                                      \
        uint4 nx = *(const uint4*)(kvbase + (size_t)(unsigned)inext * 64);     \
        float s = fdot2(cu.x, qq.x, fdot2(cu.y, qq.y, 0.f));                   \
        s = qadd_xor1(s);                                                      \
        s = qadd_xor2(s);                                                      \
        float xx = fminf(fmaxf(s * 0.25f, -5.f), 5.f);                         \
        float sc = (e + (J) < cnt) ? __expf(xx) : 0.f;                         \
        accz += sc;                                                            \
        float2 v0 = h2f(cu.z), v1 = h2f(cu.w);                                 \
        av0 += sc * v0.x; av1 += sc * v0.y;                                    \
        av2 += sc * v1.x; av3 += sc * v1.y;                                    \
        cu = nx;                                                               \
    }

__global__ __launch_bounds__(256) void aggregate_kernel(
    const unsigned* __restrict__ KVh,          // [H][N] 64B rows
    const uint2* __restrict__ Qr,              // [H][N] 4x uint2
    const int2* __restrict__ offs, const unsigned short* __restrict__ csr,
    const int* __restrict__ nodeord,
    float* __restrict__ out, int n)
{
    const int t = threadIdx.x;
    const int head = blockIdx.x & 7;
    const int rest = blockIdx.x >> 3;
    const int bkt = rest >> 1, sub = rest & 1;
    const int lane = t & 63;
    const int g = lane >> 2;          // quad (node slot) 0..15
    const int p = lane & 3;           // feature quarter
    const int chunk = ((t >> 6) << 1) | sub;   // interleave rank chunks

    const int spos = (bkt << 7) + (chunk << 4) + g;
    const int local = nodeord[spos];
    const int node = (bkt << 7) + local;
    const bool nvalid = (node < n);
    const int nodec = nvalid ? node : 0;

    int beg = 0, cnt = 0;
    if (nvalid) {
        int2 be = offs[node];
        beg = be.x; cnt = be.y - be.x;
    }

    const size_t hn = (size_t)head * n;
    const uint2 qq = Qr[(hn + nodec) * 4 + p];
    const char* kvbase = (const char*)KVh + hn * 64 + (size_t)p * 16;

    float accz = 0.f;
    float av0 = 0.f, av1 = 0.f, av2 = 0.f, av3 = 0.f;

    // prime: load first 4 csr indices (lane p -> edge p), broadcast edge 0
    const int cl = (cnt > 0) ? (cnt - 1) : 0;
    int p0 = (p < cl) ? p : cl;
    int idxq = (int)csr[beg + p0];
    int i0 = QBCAST(idxq, 0);
    uint4 cu = *(const uint4*)(kvbase + (size_t)(unsigned)i0 * 64);

    for (int e = 0; e < cnt; e += 4) {
        AGG_STEP(0, false)
        AGG_STEP(1, false)
        AGG_STEP(2, false)
        AGG_STEP(3, true)
    }

    if (nvalid) {
        float z = accz;
        if (z == 0.f) z = 0.001f;
        float inv = 1.0f / z;
        *(float4*)(out + (size_t)node * 128 + head * 16 + p * 4) =
            make_float4(av0 * inv, av1 * inv, av2 * inv, av3 * inv);
    }
}

// ---------------------------------------------------------------------------

extern "C" void kernel_launch(void* const* d_in, const int* in_sizes, int n_in,
                              void* d_out, int out_size, void* d_ws, size_t ws_size,
                              hipStream_t stream)
{
    const float* h   = (const float*)d_in[0];
    const int*   src = (const int*)d_in[1];
    const int*   dst = (const int*)d_in[2];
    const float* p   = (const float*)d_in[3];
    const float* q   = (const float*)d_in[4];
    const float* wv  = (const float*)d_in[5];
    float* out = (float*)d_out;

    const int N = in_sizes[0] / 128;
    const int E = in_sizes[1];
    const int nbkt = (N + 127) >> BKT_SHIFT;     // 391 for N=50000 (<=512)
    const int nblk_e = (E + EPB - 1) / EPB;      // 391 for E=1.6M (<=512)
    const int gemm_blocks = (N + HNODE - 1) / HNODE;   // 782

    unsigned* KV = (unsigned*)d_ws;                            // H*N*16 u32 (25.6MB)
    __half* Qh   = (__half*)(KV + (size_t)N * 128);            // H*N*16 half (12.8MB)
    unsigned* ebuf = (unsigned*)(Qh + (size_t)N * 128);        // nbkt*nblk_e*CHUNK u32 (~24.5MB)
    int* cnts    = (int*)(ebuf + (size_t)nbkt * nblk_e * CHUNK); // nblk_e*512
    unsigned short* csr16 = (unsigned short*)(cnts + (size_t)nblk_e * 512); // nbkt*BKT_CAP u16 (4MB)
    int2* offs   = (int2*)(csr16 + (size_t)nbkt * BKT_CAP);    // N
    int* nodeord = (int*)(offs + N);                           // nbkt*128
    __half* Wt   = (__half*)(nodeord + (size_t)nbkt * 128);    // 3*128*128 halves

    wt_convert_kernel<<<192, 256, 0, stream>>>(q, p, wv, Wt);

    gemm_scatter_kernel<<<gemm_blocks + nblk_e, 256, 0, stream>>>(
        h, Wt, KV, Qh, N, src, dst, ebuf, cnts, E, nbkt, nblk_e, gemm_blocks);

    fine_scatter_kernel<<<nbkt, 512, 0, stream>>>(ebuf, cnts, offs, csr16, nodeord, N, nblk_e, nbkt);

    aggregate_kernel<<<nbkt * 16, 256, 0, stream>>>(
        KV, (const uint2*)Qh, offs, csr16, nodeord, (float*)out, N);
}